// Round 1
// baseline (126.785 us; speedup 1.0000x reference)
//
#include <hip/hip_runtime.h>
#include <hip/hip_cooperative_groups.h>
#include <cmath>

#define N_GAUSS 256

namespace cg = cooperative_groups;

// ---------------------------------------------------------------------------
// Helpers shared by the cooperative kernel and the 2-kernel fallback path.
// ---------------------------------------------------------------------------

__device__ __forceinline__ float sigmoidf_fast(float w) {
  // 1/(1+exp(-w)) via hardware exp2 + IEEE divide (divide cost amortized:
  // once per gaussian per block, not in the hot loop)
  float t = __builtin_amdgcn_exp2f(-1.4426950408889634f * w);
  return 1.0f / (1.0f + t);
}

__device__ __forceinline__ void wave_reduce_minmax(float4& r) {
  for (int o = 32; o > 0; o >>= 1) {
    r.x = fminf(r.x, __shfl_down(r.x, o));
    r.y = fminf(r.y, __shfl_down(r.y, o));
    r.z = fmaxf(r.z, __shfl_down(r.z, o));
    r.w = fmaxf(r.w, __shfl_down(r.w, o));
  }
}

// Agent-scope (device-coherent) accesses: bypass the per-XCD L2 so readers on
// a different XCD cannot hit a stale (poison) line after grid.sync().
__device__ __forceinline__ void store_agent(float* p, float v) {
  __hip_atomic_store(p, v, __ATOMIC_RELAXED, __HIP_MEMORY_SCOPE_AGENT);
}
__device__ __forceinline__ float load_agent(const float* p) {
  return __hip_atomic_load(p, __ATOMIC_RELAXED, __HIP_MEMORY_SCOPE_AGENT);
}

// fp32 param fold: thread t handles gaussian t.
// Folded form: u = A*x + B*y + E, v = C*x + D*y + F, z = sqrt(u^2+v^2)
//   sp[2t] = (A, B, E, C), sp[2t+1] = (D, F, -, -)
// fp32 params verified safe previously (absmax 0.0 vs np reference).
__device__ __forceinline__ void fold_params(float4 bc, int t,
    const float* __restrict__ W_scale, const float* __restrict__ W_shape_var,
    const float* __restrict__ W_rotation, const float* __restrict__ W_offsets,
    float4* sp) {
  float cmin0 = bc.x - bc.z * 0.05f;
  float cmin1 = bc.y - bc.w * 0.05f;
  float cmax0 = bc.z + bc.z * 0.05f;
  float cmax1 = bc.w + bc.w * 0.05f;

  float sS = sigmoidf_fast(W_scale[t]);
  float base_scale = 1.45f * sS + 0.05f;
  float sV = sigmoidf_fast(W_shape_var[t]);
  float ratio = 3.0f * sV + 0.5f;
  float sR = sigmoidf_fast(W_rotation[t]);
  const float PIf = 3.14159265358979323846f;
  float rot = -0.5f * PIf + PIf * sR;
  float sOx = sigmoidf_fast(W_offsets[2 * t]);
  float sOy = sigmoidf_fast(W_offsets[2 * t + 1]);
  float ox = cmin0 + (cmax0 - cmin0) * sOx;
  float oy = cmin1 + (cmax1 - cmin1) * sOy;

  float cr = cosf(rot), sr = sinf(rot);
  float inv_s = 1.0f / (base_scale + 1e-8f);
  float r0 = rsqrtf(1.0f + 1e-6f);                 // sigma0 = 1
  float r1 = rsqrtf(fmaf(ratio, ratio, 1e-6f));    // sigma1 = ratio

  float A = r0 * cr * inv_s;
  float B = -r0 * sr * inv_s;
  float E = -fmaf(A, ox, B * oy);
  float C = r1 * sr * inv_s;
  float D = r1 * cr * inv_s;
  float F = -fmaf(C, ox, D * oy);

  sp[2 * t]     = make_float4(A, B, E, C);
  sp[2 * t + 1] = make_float4(D, F, 0.0f, 0.0f);
}

// Main per-point evaluation with wave-uniform early exit.
// All kernel terms >= 0 so ks only grows; once every lane has ks > 6,
// sigmoid(-10(ks-0.5)) < e^-55 and H == 1e-9 exactly in fp32 regardless of
// the remaining terms (matches reference's full-sum result bit-exactly).
__device__ __forceinline__ float eval_point(const float4* sp, float2 c) {
  float x = c.x, y = c.y;
  float ks = 1e-8f;
  const float K1 = 14.4269504088896339f; // 10 * log2(e)

  for (int b0 = 0; b0 < N_GAUSS; b0 += 8) {
#pragma unroll
    for (int j = 0; j < 8; ++j) {
      int b = b0 + j;
      float4 p0 = sp[2 * b];
      float4 p1 = sp[2 * b + 1];
      float u = fmaf(p0.x, x, fmaf(p0.y, y, p0.z));
      float v = fmaf(p0.w, x, fmaf(p1.x, y, p1.y));
      float z = sqrtf(fmaf(u, u, v * v));
      float tt = __builtin_amdgcn_exp2f(fmaf(K1, z, -K1));
      ks += __builtin_amdgcn_rcpf(1.0f + tt);
    }
    if (__all(ks > 6.0f)) break;
  }

  // H = (1-1e-9) * sigmoid(-10*(ks-0.5)) + 1e-9
  float t2 = __builtin_amdgcn_exp2f(fmaf(K1, ks, -0.5f * K1));
  float s = __builtin_amdgcn_rcpf(1.0f + t2);
  return fmaf(1e-9f, 1.0f - s, s);
}

// ---------------------------------------------------------------------------
// Single cooperative kernel: phase A (per-block minmax, agent-scope publish)
// -> grid.sync() -> phase B (redundant bounds reduce + param fold) -> main.
// Removes one kernel dispatch + its dependency gap vs the 2-kernel path.
// ---------------------------------------------------------------------------
__global__ __launch_bounds__(256) void k_coop(
    const float2* __restrict__ coords,
    float* __restrict__ pbuf,               // ws: gridDim.x * 4 floats
    const float* __restrict__ W_scale,
    const float* __restrict__ W_shape_var,
    const float* __restrict__ W_rotation,
    const float* __restrict__ W_offsets,
    float* __restrict__ out, int n) {
  __shared__ float4 sp[2 * N_GAUSS];
  __shared__ float4 lds4[4];
  __shared__ float4 boundsS;

  int t = threadIdx.x;
  int nb = gridDim.x;
  int nthreads = nb * 256;
  int gid = blockIdx.x * 256 + t;

  // ---- phase A: per-block partial min/max over coords ----
  float4 r = make_float4(INFINITY, INFINITY, -INFINITY, -INFINITY);
  for (int i = gid; i < n; i += nthreads) {
    float2 c = coords[i];
    r.x = fminf(r.x, c.x);
    r.y = fminf(r.y, c.y);
    r.z = fmaxf(r.z, c.x);
    r.w = fmaxf(r.w, c.y);
  }
  wave_reduce_minmax(r);
  if ((t & 63) == 0) lds4[t >> 6] = r;
  __syncthreads();
  if (t == 0) {
    float4 a = lds4[0];
    for (int w = 1; w < 4; ++w) {
      float4 o = lds4[w];
      a.x = fminf(a.x, o.x);
      a.y = fminf(a.y, o.y);
      a.z = fmaxf(a.z, o.z);
      a.w = fmaxf(a.w, o.w);
    }
    // agent-scope publish: visible device-wide, immune to stale poison lines
    store_agent(&pbuf[4 * blockIdx.x + 0], a.x);
    store_agent(&pbuf[4 * blockIdx.x + 1], a.y);
    store_agent(&pbuf[4 * blockIdx.x + 2], a.z);
    store_agent(&pbuf[4 * blockIdx.x + 3], a.w);
  }

  cg::this_grid().sync();

  // ---- phase B: redundant per-block reduce of nb partials -> bounds ----
  float4 g = make_float4(INFINITY, INFINITY, -INFINITY, -INFINITY);
  for (int s = t; s < nb; s += 256) {
    float px = load_agent(&pbuf[4 * s + 0]);
    float py = load_agent(&pbuf[4 * s + 1]);
    float pz = load_agent(&pbuf[4 * s + 2]);
    float pw = load_agent(&pbuf[4 * s + 3]);
    g.x = fminf(g.x, px);
    g.y = fminf(g.y, py);
    g.z = fmaxf(g.z, pz);
    g.w = fmaxf(g.w, pw);
  }
  wave_reduce_minmax(g);
  if ((t & 63) == 0) lds4[t >> 6] = g;
  __syncthreads();
  if (t == 0) {
    float4 a = lds4[0];
    for (int w = 1; w < 4; ++w) {
      float4 o = lds4[w];
      a.x = fminf(a.x, o.x);
      a.y = fminf(a.y, o.y);
      a.z = fmaxf(a.z, o.z);
      a.w = fmaxf(a.w, o.w);
    }
    boundsS = a;
  }
  __syncthreads();
  float4 bc = boundsS;

  fold_params(bc, t, W_scale, W_shape_var, W_rotation, W_offsets, sp);
  __syncthreads();

  // ---- main loop ----
  for (int i = gid; i < n; i += nthreads) {
    out[i] = eval_point(sp, coords[i]);
  }
}

// ---------------------------------------------------------------------------
// Fallback: proven 2-kernel path (identical to the previous best kernel),
// used only if the cooperative launch is rejected by the runtime/capture.
// ---------------------------------------------------------------------------
__global__ __launch_bounds__(256) void k_partial_minmax(
    const float2* __restrict__ coords, int n, float4* __restrict__ partial) {
  int tid = blockIdx.x * blockDim.x + threadIdx.x;
  int stride = gridDim.x * blockDim.x;
  float4 r = make_float4(INFINITY, INFINITY, -INFINITY, -INFINITY);
  for (int i = tid; i < n; i += stride) {
    float2 c = coords[i];
    r.x = fminf(r.x, c.x);
    r.y = fminf(r.y, c.y);
    r.z = fmaxf(r.z, c.x);
    r.w = fmaxf(r.w, c.y);
  }
  wave_reduce_minmax(r);
  __shared__ float4 lds[4];
  if ((threadIdx.x & 63) == 0) lds[threadIdx.x >> 6] = r;
  __syncthreads();
  if (threadIdx.x == 0) {
    float4 a = lds[0];
    for (int w = 1; w < 4; ++w) {
      float4 o = lds[w];
      a.x = fminf(a.x, o.x);
      a.y = fminf(a.y, o.y);
      a.z = fmaxf(a.z, o.z);
      a.w = fmaxf(a.w, o.w);
    }
    partial[blockIdx.x] = a;
  }
}

__global__ __launch_bounds__(256) void k_fused_main(
    const float2* __restrict__ coords,
    const float4* __restrict__ partial,
    const float* __restrict__ W_scale,
    const float* __restrict__ W_shape_var,
    const float* __restrict__ W_rotation,
    const float* __restrict__ W_offsets,
    float* __restrict__ out, int n) {
  __shared__ float4 sp[2 * N_GAUSS];
  __shared__ float4 lds4[4];
  __shared__ float4 boundsS;

  int t = threadIdx.x;

  float4 r = partial[t];
  wave_reduce_minmax(r);
  if ((t & 63) == 0) lds4[t >> 6] = r;
  __syncthreads();
  if (t == 0) {
    float4 a = lds4[0];
    for (int w = 1; w < 4; ++w) {
      float4 o = lds4[w];
      a.x = fminf(a.x, o.x);
      a.y = fminf(a.y, o.y);
      a.z = fmaxf(a.z, o.z);
      a.w = fmaxf(a.w, o.w);
    }
    boundsS = a;
  }
  __syncthreads();
  float4 bc = boundsS;

  fold_params(bc, t, W_scale, W_shape_var, W_rotation, W_offsets, sp);
  __syncthreads();

  int i = blockIdx.x * blockDim.x + threadIdx.x;
  if (i >= n) return;
  out[i] = eval_point(sp, coords[i]);
}

extern "C" void kernel_launch(void* const* d_in, const int* in_sizes, int n_in,
                              void* d_out, int out_size, void* d_ws, size_t ws_size,
                              hipStream_t stream) {
  const float2* coords     = (const float2*)d_in[0];
  const float* W_scale     = (const float*)d_in[1];
  const float* W_shape_var = (const float*)d_in[2];
  const float* W_rotation  = (const float*)d_in[3];
  const float* W_offsets   = (const float*)d_in[4];
  float* out = (float*)d_out;

  int n = in_sizes[0] / 2; // coords is (N,2)

  // workspace: [0, blocks*16) per-block partial min/max
  float* pbuf = (float*)d_ws;

  int blocks = (n + 255) / 256;
  if (blocks > 512) blocks = 512;   // 2 blocks/CU co-residency; grid-stride covers rest

  void* args[] = {(void*)&coords, (void*)&pbuf, (void*)&W_scale,
                  (void*)&W_shape_var, (void*)&W_rotation, (void*)&W_offsets,
                  (void*)&out, (void*)&n};
  hipError_t err = hipLaunchCooperativeKernel((const void*)k_coop, dim3(blocks),
                                              dim3(256), args, 0, stream);
  if (err != hipSuccess) {
    // proven 2-kernel fallback (kernel-boundary coherence, no fences needed)
    float4* partial = (float4*)d_ws;
    k_partial_minmax<<<256, 256, 0, stream>>>(coords, n, partial);
    int b2 = (n + 255) / 256;
    k_fused_main<<<b2, 256, 0, stream>>>(coords, partial, W_scale, W_shape_var,
                                         W_rotation, W_offsets, out, n);
  }
}

// Round 2
// 66.991 us; speedup vs baseline: 1.8926x; 1.8926x over previous
//
#include <hip/hip_runtime.h>
#include <cmath>

#define N_GAUSS 256

// ---------------------------------------------------------------------------
// Kernel 1: per-block partial min/max of coords (x,y). 256 blocks x 256 thr.
// partial[block] = (minx, miny, maxx, maxy)
// float4 loads: each load covers 2 points (x0,y0,x1,y1). min/max is exactly
// order-insensitive, so vectorization is bit-exact vs the scalar version.
// ---------------------------------------------------------------------------
__global__ __launch_bounds__(256) void k_partial_minmax(
    const float4* __restrict__ coords4, int n, float4* __restrict__ partial) {
  int tid = blockIdx.x * blockDim.x + threadIdx.x;
  int stride = gridDim.x * blockDim.x;
  int n4 = n >> 1;  // pairs of points
  float mnx = INFINITY, mny = INFINITY, mxx = -INFINITY, mxy = -INFINITY;
  for (int i = tid; i < n4; i += stride) {
    float4 c = coords4[i];
    mnx = fminf(mnx, fminf(c.x, c.z));
    mny = fminf(mny, fminf(c.y, c.w));
    mxx = fmaxf(mxx, fmaxf(c.x, c.z));
    mxy = fmaxf(mxy, fmaxf(c.y, c.w));
  }
  if (tid == 0 && (n & 1)) {  // odd tail point
    const float2* c2 = (const float2*)coords4;
    float2 c = c2[n - 1];
    mnx = fminf(mnx, c.x);
    mny = fminf(mny, c.y);
    mxx = fmaxf(mxx, c.x);
    mxy = fmaxf(mxy, c.y);
  }
  // wave-64 shuffle reduction
  for (int o = 32; o > 0; o >>= 1) {
    mnx = fminf(mnx, __shfl_down(mnx, o));
    mny = fminf(mny, __shfl_down(mny, o));
    mxx = fmaxf(mxx, __shfl_down(mxx, o));
    mxy = fmaxf(mxy, __shfl_down(mxy, o));
  }
  __shared__ float4 lds[4];
  if ((threadIdx.x & 63) == 0) lds[threadIdx.x >> 6] = make_float4(mnx, mny, mxx, mxy);
  __syncthreads();
  if (threadIdx.x == 0) {
    float4 r = lds[0];
    for (int w = 1; w < 4; ++w) {
      float4 o = lds[w];
      r.x = fminf(r.x, o.x);
      r.y = fminf(r.y, o.y);
      r.z = fmaxf(r.z, o.z);
      r.w = fmaxf(r.w, o.w);
    }
    partial[blockIdx.x] = r;
  }
}

__device__ __forceinline__ float sigmoidf_fast(float w) {
  // 1/(1+exp(-w)) via hardware exp2 + IEEE divide (divide cost is amortized:
  // once per gaussian per block, not in the hot loop)
  float t = __builtin_amdgcn_exp2f(-1.4426950408889634f * w);
  return 1.0f / (1.0f + t);
}

// ---------------------------------------------------------------------------
// Kernel 2 (fused): per-block redundant {partial-reduce -> bounds -> fp32
// per-gaussian param fold into LDS}, then the early-exit main loop.
//
// Folded form: u = A*x + B*y + E, v = C*x + D*y + F, z = sqrt(u^2+v^2)
//   sp[2b]   = (A, B, E, C)
//   sp[2b+1] = (D, F, -, -)
//
// fp32 params are safe: the output H is saturated at 1e-9 (sigma-term
// < 1e-24), insensitive to O(1e-6) relative param error (verified: absmax
// 0.0 vs np reference with the fp64 variant; sensitivity analysis puts the
// fp32-induced error ~14 orders below the 2e-11 threshold).
//
// Early exit: all kernel terms >= 0 so ks only grows; once every lane has
// ks > 6, sigmoid(-10(ks-0.5)) < e^-55 and H == 1e-9 regardless of the
// remaining terms.
//
// NOTE (R1 post-mortem): do NOT fuse k1+k2 via cooperative grid.sync() —
// measured 52 µs of idle per launch (device-scope fences => per-block L2
// writeback + global spin on this runtime). Two plain dispatches are far
// cheaper than one grid barrier on MI355X.
// ---------------------------------------------------------------------------
__global__ __launch_bounds__(256) void k_fused_main(
    const float2* __restrict__ coords,
    const float4* __restrict__ partial,
    const float* __restrict__ W_scale,
    const float* __restrict__ W_shape_var,
    const float* __restrict__ W_rotation,
    const float* __restrict__ W_offsets,
    float* __restrict__ out, int n) {
  __shared__ float4 sp[2 * N_GAUSS];
  __shared__ float4 lds4[4];
  __shared__ float4 boundsS;

  int t = threadIdx.x;

  // ---- reduce the 256 partials to global bounds (redundant per block) ----
  float4 r = partial[t];
  for (int o = 32; o > 0; o >>= 1) {
    r.x = fminf(r.x, __shfl_down(r.x, o));
    r.y = fminf(r.y, __shfl_down(r.y, o));
    r.z = fmaxf(r.z, __shfl_down(r.z, o));
    r.w = fmaxf(r.w, __shfl_down(r.w, o));
  }
  if ((t & 63) == 0) lds4[t >> 6] = r;
  __syncthreads();
  if (t == 0) {
    float4 a = lds4[0];
    for (int w = 1; w < 4; ++w) {
      float4 o = lds4[w];
      a.x = fminf(a.x, o.x);
      a.y = fminf(a.y, o.y);
      a.z = fmaxf(a.z, o.z);
      a.w = fmaxf(a.w, o.w);
    }
    boundsS = a;
  }
  __syncthreads();
  float4 bc = boundsS;

  // ---- fp32 param fold: thread t handles gaussian t ----
  {
    float cmin0 = bc.x - bc.z * 0.05f;
    float cmin1 = bc.y - bc.w * 0.05f;
    float cmax0 = bc.z + bc.z * 0.05f;
    float cmax1 = bc.w + bc.w * 0.05f;

    float sS = sigmoidf_fast(W_scale[t]);
    float base_scale = 1.45f * sS + 0.05f;
    float sV = sigmoidf_fast(W_shape_var[t]);
    float ratio = 3.0f * sV + 0.5f;
    float sR = sigmoidf_fast(W_rotation[t]);
    const float PIf = 3.14159265358979323846f;
    float rot = -0.5f * PIf + PIf * sR;
    float sOx = sigmoidf_fast(W_offsets[2 * t]);
    float sOy = sigmoidf_fast(W_offsets[2 * t + 1]);
    float ox = cmin0 + (cmax0 - cmin0) * sOx;
    float oy = cmin1 + (cmax1 - cmin1) * sOy;

    float cr = cosf(rot), sr = sinf(rot);
    float inv_s = 1.0f / (base_scale + 1e-8f);
    float r0 = rsqrtf(1.0f + 1e-6f);                   // sigma0 = 1
    float r1 = rsqrtf(fmaf(ratio, ratio, 1e-6f));      // sigma1 = ratio

    float A = r0 * cr * inv_s;
    float B = -r0 * sr * inv_s;
    float E = -fmaf(A, ox, B * oy);
    float C = r1 * sr * inv_s;
    float D = r1 * cr * inv_s;
    float F = -fmaf(C, ox, D * oy);

    sp[2 * t]     = make_float4(A, B, E, C);
    sp[2 * t + 1] = make_float4(D, F, 0.0f, 0.0f);
  }
  __syncthreads();

  // ---- main loop with wave-uniform early exit ----
  int i = blockIdx.x * blockDim.x + threadIdx.x;
  if (i >= n) return;
  float2 c = coords[i];
  float x = c.x, y = c.y;
  float ks = 1e-8f;
  const float K1 = 14.4269504088896339f; // 10 * log2(e)

  for (int b0 = 0; b0 < N_GAUSS; b0 += 8) {
#pragma unroll
    for (int j = 0; j < 8; ++j) {
      int b = b0 + j;
      float4 p0 = sp[2 * b];
      float4 p1 = sp[2 * b + 1];
      float u = fmaf(p0.x, x, fmaf(p0.y, y, p0.z));
      float v = fmaf(p0.w, x, fmaf(p1.x, y, p1.y));
      float z = sqrtf(fmaf(u, u, v * v));
      float tt = __builtin_amdgcn_exp2f(fmaf(K1, z, -K1));
      ks += __builtin_amdgcn_rcpf(1.0f + tt);
    }
    if (__all(ks > 6.0f)) break;
  }

  // H = (1-1e-9) * sigmoid(-10*(ks-0.5)) + 1e-9
  float t2 = __builtin_amdgcn_exp2f(fmaf(K1, ks, -0.5f * K1));
  float s = __builtin_amdgcn_rcpf(1.0f + t2);
  out[i] = fmaf(1e-9f, 1.0f - s, s);
}

extern "C" void kernel_launch(void* const* d_in, const int* in_sizes, int n_in,
                              void* d_out, int out_size, void* d_ws, size_t ws_size,
                              hipStream_t stream) {
  const float* coords      = (const float*)d_in[0];
  const float* W_scale     = (const float*)d_in[1];
  const float* W_shape_var = (const float*)d_in[2];
  const float* W_rotation  = (const float*)d_in[3];
  const float* W_offsets   = (const float*)d_in[4];
  float* out = (float*)d_out;

  int n = in_sizes[0] / 2; // coords is (N,2)

  // workspace: [0,4096) partial min/max (256 float4)
  float4* partial = (float4*)d_ws;

  k_partial_minmax<<<256, 256, 0, stream>>>((const float4*)coords, n, partial);
  int blocks = (n + 255) / 256;
  k_fused_main<<<blocks, 256, 0, stream>>>((const float2*)coords, partial,
                                           W_scale, W_shape_var, W_rotation,
                                           W_offsets, out, n);
}